// Round 1
// baseline (441.010 us; speedup 1.0000x reference)
//
#include <hip/hip_runtime.h>
#include <math.h>

typedef unsigned int u32;

#define BSZ   16
#define CCH   256
#define TT    768
#define PT    12
#define NPN   64
#define NH    4
#define GRID  BSZ            /* 16 blocks: one per batch element, all 256 channels */
#define THR   768            /* 12 waves: wave = patch, lane owns channels l,l+64,l+128,l+192 */

/* ---- workspace float offsets (unchanged layout; exchange region now unused) ---- */
#define WS_A    0
#define WS_CCF  4
#define WS_POLY 8              /* 15 quadratic coefficients */
#define WS_WAGG 80
#define WS_BAGG 224
#define WS_G1T  256            /* [j][c] g1[c,j]*INVSF */
#define WS_B1T  3328
#define WS_G2T  6400
#define WS_B2T  9472
#define WS_XN   32768          /* [16][768][256] BN0-folded x, (t*12+p, c) layout */

#define INVSF 0.9999950000374996f
#define K2F   0.3989422804014327f   /* 1/sqrt(2*pi) */

__device__ __forceinline__ float med3f(float a, float b, float c){
  return fmaxf(fminf(a,b), fminf(fmaxf(a,b), c));
}
__device__ __forceinline__ float gelu_fast(float v){
  float av = fabsf(v);
  if (__builtin_expect(av > 1.0f, 0))
    return 0.5f * v * (1.0f + erff(v * 0.7071067811865475f));
  float t = v * v;
  float r = 1.3319545e-06f;
  r = fmaf(r, t, -1.8889312e-05f);
  r = fmaf(r, t,  2.3086939e-04f);
  r = fmaf(r, t, -2.3746564e-03f);
  r = fmaf(r, t,  1.9947114e-02f);
  r = fmaf(r, t, -1.3298076e-01f);
  r = fmaf(r, t,  7.9788456e-01f);
  float a = 0.5f * v;
  return fmaf(a * v, r, a);
}
/* e^x for |x| <~ 0.05: cubic Taylor, err < 1e-7 */
__device__ __forceinline__ float exp_t3(float x){
  float t = fmaf(x, 0.3333333333f, 1.0f);
  t = fmaf(x * 0.5f, t, 1.0f);
  return fmaf(x, t, 1.0f);
}
__device__ __forceinline__ float rdlane(float v, int lane){
  return __int_as_float(__builtin_amdgcn_readlane(__float_as_int(v), lane));
}

/* merge sorted triple (T1>=T2>=T3) with DPP-shifted peer triple (identity -1e30 on invalid lanes) */
#define TRIPLE_STAGE3(T1,T2,T3,CTRL) { \
  float o1 = __int_as_float(__builtin_amdgcn_update_dpp(ni, __float_as_int(T1), CTRL, 0xf, 0xf, false)); \
  float o2 = __int_as_float(__builtin_amdgcn_update_dpp(ni, __float_as_int(T2), CTRL, 0xf, 0xf, false)); \
  float o3 = __int_as_float(__builtin_amdgcn_update_dpp(ni, __float_as_int(T3), CTRL, 0xf, 0xf, false)); \
  float yy = fminf(T1,o1), xx = fmaxf(T2,o2); \
  T1 = fmaxf(T1,o1); \
  float n3 = med3f(yy, xx, fmaxf(T3,o3)); \
  T2 = fmaxf(yy,xx); T3 = n3; }

/* ------------ precompute (block 0) + coalesced tile-transpose fold (1..768) ------------ */
__global__ __launch_bounds__(1024) void precompute_kernel(
    const float* __restrict__ x,   const float* __restrict__ g0,
    const float* __restrict__ b0,
    const float* __restrict__ gg1, const float* __restrict__ bb1,
    const float* __restrict__ gg2, const float* __restrict__ bb2,
    const float* __restrict__ Wagg, const float* __restrict__ bagg,
    const float* __restrict__ We,  const float* __restrict__ be,
    const float* __restrict__ Wq,  const float* __restrict__ bq,
    const float* __restrict__ Wk,  const float* __restrict__ bk,
    const float* __restrict__ Wv,  const float* __restrict__ bv,
    const float* __restrict__ Wm1, const float* __restrict__ bm1,
    const float* __restrict__ Wm2, const float* __restrict__ bm2,
    float* __restrict__ ws)
{
  const int tid = threadIdx.x;

  if (blockIdx.x != 0) {
    /* fold: xn[b][tim][c] = BN0(x)[b][c][tim]; 4 32x32 tiles per block, coalesced */
    __shared__ float tile[4][32*33];
    const int tau = (blockIdx.x - 1)*4 + (tid >> 8);   /* 0..3071 */
    const int b   = tau / 192;
    const int rem = tau - b*192;
    const int t0  = (rem % 24) * 32;
    const int c0  = (rem / 24) * 32;
    const int tx  = tid & 31;
    const int ty  = (tid >> 5) & 7;
    float* tl = &tile[tid >> 8][0];
    const long xb = (long)b * (CCH*TT);
    #pragma unroll
    for (int r = 0; r < 4; ++r) {
      int c = c0 + ty + r*8;
      int ict = c*TT + t0 + tx;
      tl[(ty + r*8)*33 + tx] = fmaf(x[xb + ict], g0[ict]*INVSF, b0[ict]);
    }
    __syncthreads();
    #pragma unroll
    for (int r = 0; r < 4; ++r) {
      int tt = t0 + ty + r*8;
      ws[WS_XN + ((long)b*TT + tt)*CCH + c0 + tx] = tl[tx*33 + ty + r*8];
    }
    return;
  }

  __shared__ float We_s[CCH], be_s[CCH];
  __shared__ float wq_s[CCH], cq_s[CCH], wk_s[CCH], wv_s[CCH], cv_s[CCH];
  __shared__ float M_l[CCH*4], cm1_l[CCH], wm2_l[CCH];
  const int lane = tid & 63;
  const int w    = tid >> 6;

  if (tid < CCH) { We_s[tid] = We[tid]; be_s[tid] = be[tid]; wm2_l[tid] = Wm2[tid]; }
  __syncthreads();

  for (int f = w; f < CCH; f += 16) {
    float aq=0.f, cqa=0.f, ak=0.f, av=0.f, cva=0.f;
    #pragma unroll
    for (int k2 = 0; k2 < 4; ++k2) {
      int j = lane + 64*k2;
      float wev = We_s[j], bev = be_s[j];
      float q1 = Wq[f*CCH + j]; aq += q1*wev; cqa += q1*bev;
      float k1 = Wk[f*CCH + j]; ak += k1*wev;
      float v1 = Wv[f*CCH + j]; av += v1*wev; cva += v1*bev;
    }
    for (int ofs = 1; ofs < 64; ofs <<= 1) {
      aq += __shfl_xor(aq, ofs);  cqa += __shfl_xor(cqa, ofs);
      ak += __shfl_xor(ak, ofs);
      av += __shfl_xor(av, ofs);  cva += __shfl_xor(cva, ofs);
    }
    if (lane == 0) {
      wq_s[f] = aq; cq_s[f] = cqa + bq[f];
      wk_s[f] = ak;
      wv_s[f] = av; cv_s[f] = cva + bv[f];
    }
  }
  __syncthreads();

  if (w < NH) {
    int f = w*64 + lane;
    float a  = wq_s[f]*wk_s[f];
    float cc = cq_s[f]*wk_s[f];
    for (int ofs = 1; ofs < 64; ofs <<= 1) { a += __shfl_xor(a, ofs); cc += __shfl_xor(cc, ofs); }
    if (lane == 0) { ws[WS_A + w] = a * 0.125f; ws[WS_CCF + w] = cc * 0.125f; }
  }

  for (int g = w; g < CCH; g += 16) {
    float mk0=0.f, mk1=0.f, mk2=0.f, mk3=0.f, ca=0.f;
    #pragma unroll
    for (int k2 = 0; k2 < 4; ++k2) {
      int j = lane + 64*k2;
      float wv1 = Wm1[g*CCH + j];
      float pm = wv1 * wv_s[j];
      if (k2 == 0) mk0 = pm; else if (k2 == 1) mk1 = pm; else if (k2 == 2) mk2 = pm; else mk3 = pm;
      ca += wv1 * cv_s[j];
    }
    for (int ofs = 1; ofs < 64; ofs <<= 1) {
      mk0 += __shfl_xor(mk0, ofs); mk1 += __shfl_xor(mk1, ofs);
      mk2 += __shfl_xor(mk2, ofs); mk3 += __shfl_xor(mk3, ofs);
      ca  += __shfl_xor(ca,  ofs);
    }
    if (lane == 0) {
      M_l[g*4+0] = mk0; M_l[g*4+1] = mk1; M_l[g*4+2] = mk2; M_l[g*4+3] = mk3;
      cm1_l[g] = ca + bm1[g];
    }
  }

  for (int i = tid; i < PT*CCH; i += 1024) {
    int j = i >> 8, c = i & 255;
    ws[WS_G1T + i] = gg1[c*PT + j] * INVSF;
    ws[WS_B1T + i] = bb1[c*PT + j];
    ws[WS_G2T + i] = gg2[c*PT + j] * INVSF;
    ws[WS_B2T + i] = bb2[c*PT + j];
  }
  if (tid < PT*PT) ws[WS_WAGG + tid] = Wagg[tid];
  if (tid < PT)    ws[WS_BAGG + tid] = bagg[tid];
  __syncthreads();

  /* quadratic collapse: z(S1) = sum_g Wm2_g*(0.5u + K2 u^2), u = M[g,:].S1 + cm1_g */
  if (w < 15) {
    const int ph[10] = {0,0,0,0,1,1,1,2,2,3};
    const int pk[10] = {0,1,2,3,1,2,3,2,3,3};
    float acc = 0.f;
    for (int g = lane; g < CCH; g += 64) {
      float W = wm2_l[g], cg = cm1_l[g];
      float val;
      if (w == 0)       val = fmaf(K2F*cg, cg, 0.5f*cg);
      else if (w <= 4)  val = (0.5f + 2.f*K2F*cg) * M_l[g*4 + (w-1)];
      else {
        int hh = ph[w-5], kk = pk[w-5];
        val = K2F * M_l[g*4+hh] * M_l[g*4+kk] * (hh == kk ? 1.f : 2.f);
      }
      acc += W * val;
    }
    for (int ofs = 1; ofs < 64; ofs <<= 1) acc += __shfl_xor(acc, ofs);
    if (lane == 0) ws[WS_POLY + w] = acc + (w == 0 ? bm2[0] : 0.f);
  }
}

/* ------------ main: 16 blocks x 768 thr; 4 channels/lane; all-intra-block reduction ------ */
__global__ __launch_bounds__(THR, 3) void main_kernel(float* __restrict__ ws, float* __restrict__ out)
{
  const int b   = blockIdx.x;          /* one block per batch element */
  const int tid = threadIdx.x;
  const int p   = tid >> 6;            /* wave = patch position */
  const int l   = tid & 63;            /* lane owns channels l, l+64, l+128, l+192 */

  __shared__ float tmp_sh[2][PT][CCH];        /* 24.0 KB, bank = l%32 -> free 2-way */
  __shared__ float o_buf[3][PT][CCH + 2];     /* 36.3 KB, +2 pad spreads flush-read banks */
  __shared__ float C_lds[15];

  if (tid < 15) C_lds[tid] = ws[WS_POLY + tid];

  float g1r[4], b1r[4], g2r[4], b2r[4];
  #pragma unroll
  for (int q = 0; q < 4; ++q) {
    const int cg = l + 64*q;
    g1r[q] = ws[WS_G1T + p*CCH + cg];
    b1r[q] = ws[WS_B1T + p*CCH + cg];
    g2r[q] = ws[WS_G2T + p*CCH + cg];
    b2r[q] = ws[WS_B2T + p*CCH + cg];
  }
  float waggr[PT];
  #pragma unroll
  for (int j = 0; j < PT; ++j) waggr[j] = ws[WS_WAGG + p*PT + j];
  const float baggp = ws[WS_BAGG + p];
  float Ah[NH], Ch[NH];
  #pragma unroll
  for (int h = 0; h < NH; ++h) { Ah[h] = ws[WS_A + h]; Ch[h] = ws[WS_CCF + h]; }
  __syncthreads();

  float C15[15];
  #pragma unroll
  for (int m = 0; m < 15; ++m)
    C15[m] = __int_as_float(__builtin_amdgcn_readfirstlane(__float_as_int(C_lds[m])));

  const long xb  = (long)b * (CCH*TT);
  const float* xnb = ws + WS_XN + (long)b*(TT*CCH);
  const int ni = __float_as_int(-1e30f);       /* DPP identity */

  /* t = 0 */
  float st[4];
  #pragma unroll
  for (int q = 0; q < 4; ++q) {
    st[q] = xnb[(long)p*CCH + l + 64*q];
    o_buf[0][p][l + 64*q] = st[q];
  }
  /* prefetch t = 1 */
  float xv[4];
  #pragma unroll
  for (int q = 0; q < 4; ++q)
    xv[q] = xnb[((long)PT + p)*CCH + l + 64*q];

  for (int t = 1; t < NPN; ++t) {
    const int par = t & 1;

    /* prefetch t+1 (full step of latency cover) */
    float xvn[4];
    const int tn = (t < NPN-1) ? t+1 : t;
    #pragma unroll
    for (int q = 0; q < 4; ++q)
      xvn[q] = xnb[((long)tn*PT + p)*CCH + l + 64*q];

    /* overlapped flush of step t-2 */
    if (t >= 2) {
      const int tt   = t - 2;
      const int c    = tid / PT;          /* 0..63 */
      const int part = tid - c*PT;        /* 0..11 */
      #pragma unroll
      for (int q = 0; q < 4; ++q)
        out[xb + (long)(c + 64*q)*TT + tt*PT + part] = o_buf[tt % 3][part][c + 64*q];
    }

    /* phase 1: tmp = BN1(state) */
    #pragma unroll
    for (int q = 0; q < 4; ++q)
      tmp_sh[par][p][l + 64*q] = fmaf(st[q], g1r[q], b1r[q]);
    __syncthreads();

    /* phase 2: agg + gelu + residual; s */
    float s[4], res[4];
    #pragma unroll
    for (int q = 0; q < 4; ++q) {
      float acc = baggp;
      #pragma unroll
      for (int j = 0; j < PT; ++j)
        acc = fmaf(tmp_sh[par][j][l + 64*q], waggr[j], acc);
      res[q] = gelu_fast(acc) + xv[q];
      s[q]   = fmaf(res[q], g2r[q], b2r[q]);
    }

    /* fallback for alpha==0: mean of channels 0,1,2 (lanes 0-2, q=0) */
    const float FB = (rdlane(s[0],0) + rdlane(s[0],1) + rdlane(s[0],2)) * (1.0f/3.0f);

    /* phase 3: local sorted triples over own 4 channels (top on s, bottom via -s) */
    float t1 = fmaxf(s[0], s[1]), t2 = fminf(s[0], s[1]), t3 = -1e30f;
    #pragma unroll
    for (int q = 2; q < 4; ++q) {
      const float v  = s[q];
      const float n2 = med3f(t1, t2, v);
      const float n3 = med3f(t2, t3, v);
      t1 = fmaxf(t1, v); t2 = n2; t3 = n3;
    }
    float u1 = fmaxf(-s[0], -s[1]), u2 = fminf(-s[0], -s[1]), u3 = -1e30f;
    #pragma unroll
    for (int q = 2; q < 4; ++q) {
      const float v  = -s[q];
      const float n2 = med3f(u1, u2, v);
      const float n3 = med3f(u2, u3, v);
      u1 = fmaxf(u1, v); u2 = n2; u3 = n3;
    }

    /* wave butterfly: row_shr 1/2/4/8 + row_bcast15 -> lane31 = lanes 0-31, lane63 = 32-63 */
    TRIPLE_STAGE3(t1,t2,t3, 0x111);  TRIPLE_STAGE3(u1,u2,u3, 0x111);
    TRIPLE_STAGE3(t1,t2,t3, 0x112);  TRIPLE_STAGE3(u1,u2,u3, 0x112);
    TRIPLE_STAGE3(t1,t2,t3, 0x114);  TRIPLE_STAGE3(u1,u2,u3, 0x114);
    TRIPLE_STAGE3(t1,t2,t3, 0x118);  TRIPLE_STAGE3(u1,u2,u3, 0x118);
    TRIPLE_STAGE3(t1,t2,t3, 0x142);  TRIPLE_STAGE3(u1,u2,u3, 0x142);

    float T1, T2, T3, U1, U2, U3;
    {
      const float a1 = rdlane(t1,31), a2 = rdlane(t2,31), a3 = rdlane(t3,31);
      const float q1 = rdlane(t1,63), q2 = rdlane(t2,63), q3 = rdlane(t3,63);
      const float x1 = fminf(a1,q1), y1 = fmaxf(a2,q2);
      T1 = fmaxf(a1,q1);
      T3 = med3f(x1, y1, fmaxf(a3,q3));
      T2 = fmaxf(x1,y1);
    }
    {
      const float a1 = rdlane(u1,31), a2 = rdlane(u2,31), a3 = rdlane(u3,31);
      const float q1 = rdlane(u1,63), q2 = rdlane(u2,63), q3 = rdlane(u3,63);
      const float x1 = fminf(a1,q1), y1 = fmaxf(a2,q2);
      U1 = fmaxf(a1,q1);
      U3 = med3f(x1, y1, fmaxf(a3,q3));
      U2 = fmaxf(x1,y1);
    }
    const float B1 = -U1, B2 = -U2, B3 = -U3;
    const float Td2 = T2 - T1, Td3 = T3 - T1;
    const float Bd2 = B2 - B1, Bd3 = B3 - B1;

    /* phase 4: S1 per head per channel -> quadratic z -> new state */
    #pragma unroll
    for (int q = 0; q < 4; ++q) {
      float S1v[NH];
      #pragma unroll
      for (int h = 0; h < NH; ++h) {
        const float alpha = fmaf(Ah[h], s[q], Ch[h]);
        const bool pos = alpha > 0.0f;
        const float v1s = pos ? T1 : B1;
        const float v2s = pos ? T2 : B2;
        const float v3s = pos ? T3 : B3;
        const float d2  = pos ? Td2 : Bd2;
        const float d3  = pos ? Td3 : Bd3;
        const float e2 = exp_t3(alpha * d2);
        const float e3 = exp_t3(alpha * d3);
        const float num = fmaf(e2, v2s, fmaf(e3, v3s, v1s));
        const float den = (1.0f + e2) + e3;
        const float r = __fdividef(num, den);
        S1v[h] = (alpha == 0.0f) ? FB : r;
      }
      {
        const float a = S1v[0], bb = S1v[1], c = S1v[2], d = S1v[3];
        float z = C15[0];
        z = fmaf(C15[1], a, z);   z = fmaf(C15[2], bb, z);
        z = fmaf(C15[3], c, z);   z = fmaf(C15[4], d, z);
        z = fmaf(C15[5],  a*a, z);   z = fmaf(C15[6],  a*bb, z);
        z = fmaf(C15[7],  a*c, z);   z = fmaf(C15[8],  a*d, z);
        z = fmaf(C15[9],  bb*bb, z); z = fmaf(C15[10], bb*c, z);
        z = fmaf(C15[11], bb*d, z);  z = fmaf(C15[12], c*c, z);
        z = fmaf(C15[13], c*d, z);   z = fmaf(C15[14], d*d, z);
        st[q] = fmaf(0.5f, z, res[q]);
      }
      o_buf[t % 3][p][l + 64*q] = st[q];
    }

    #pragma unroll
    for (int q = 0; q < 4; ++q) xv[q] = xvn[q];
  }

  /* tail: flush steps 62 and 63 */
  __syncthreads();
  {
    const int c    = tid / PT;
    const int part = tid - c*PT;
    #pragma unroll
    for (int tt = NPN-2; tt < NPN; ++tt) {
      #pragma unroll
      for (int q = 0; q < 4; ++q)
        out[xb + (long)(c + 64*q)*TT + tt*PT + part] = o_buf[tt % 3][part][c + 64*q];
    }
  }
}

extern "C" void kernel_launch(void* const* d_in, const int* in_sizes, int n_in,
                              void* d_out, int out_size, void* d_ws, size_t ws_size,
                              hipStream_t stream) {
  (void)in_sizes; (void)n_in; (void)out_size; (void)ws_size;
  const float* x    = (const float*)d_in[0];
  const float* g0   = (const float*)d_in[1];
  const float* b0   = (const float*)d_in[2];
  const float* gg1  = (const float*)d_in[3];
  const float* bb1  = (const float*)d_in[4];
  const float* gg2  = (const float*)d_in[5];
  const float* bb2  = (const float*)d_in[6];
  const float* Wagg = (const float*)d_in[7];
  const float* bagg = (const float*)d_in[8];
  const float* We   = (const float*)d_in[9];
  const float* be   = (const float*)d_in[10];
  const float* Wq   = (const float*)d_in[11];
  const float* bq   = (const float*)d_in[12];
  const float* Wk   = (const float*)d_in[13];
  const float* bk   = (const float*)d_in[14];
  const float* Wv   = (const float*)d_in[15];
  const float* bv   = (const float*)d_in[16];
  const float* Wm1  = (const float*)d_in[17];
  const float* bm1  = (const float*)d_in[18];
  const float* Wm2  = (const float*)d_in[19];
  const float* bm2  = (const float*)d_in[20];
  float* ws  = (float*)d_ws;
  float* out = (float*)d_out;

  hipLaunchKernelGGL(precompute_kernel, dim3(1 + 768), dim3(1024), 0, stream,
                     x, g0, b0,
                     gg1, bb1, gg2, bb2, Wagg, bagg, We, be,
                     Wq, bq, Wk, bk, Wv, bv, Wm1, bm1, Wm2, bm2, ws);
  hipLaunchKernelGGL(main_kernel, dim3(GRID), dim3(THR), 0, stream, ws, out);
}

// Round 3
// 314.952 us; speedup vs baseline: 1.4002x; 1.4002x over previous
//
#include <hip/hip_runtime.h>
#include <math.h>

typedef unsigned int u32;
typedef unsigned long long u64;

#define BSZ   16
#define CCH   256
#define TT    768
#define PT    12
#define NPN   64
#define NH    4
#define NSL   4
#define GRID  (BSZ*NSL)      /* 64 blocks: blk = slice*16 + b ; 64 channels each */
#define THR   768            /* 12 waves: wave = p, lane = channel-in-slice */

/* ---- workspace float offsets ---- */
#define WS_A    0
#define WS_CCF  4
#define WS_POLY 8              /* (unused now; poly computed in main prologue) */
#define WS_WAGG 80
#define WS_BAGG 224
#define WS_G1T  256            /* [j][c] g1[c,j]*INVSF */
#define WS_B1T  3328
#define WS_G2T  6400
#define WS_B2T  9472
/* param-fold intermediates (were block0 LDS; now ws-resident between kernels) */
#define WS_S1Q  12544          /* wq[f]  : Wq row . We            */
#define WS_S1CQ 12800          /* cq[f]  : Wq row . be + bq       */
#define WS_S1K  13056          /* wk[f]  : Wk row . We            */
#define WS_S1V  13312          /* wv[f]  : Wv row . We            */
#define WS_S1CV 13568          /* cv[f]  : Wv row . be + bv       */
#define WS_M    13824          /* [g][4] Wm1 row . wv, 64-chunked */
#define WS_CM1  14848          /* cm1[g] : Wm1 row . cv + bm1     */
#define WS_EXF  16384          /* u64 exchange region (float offset) */
#define WS_XN   32768          /* [16][768][256] BN0-folded x, (t*12+p, c) layout */

#define INVSF 0.9999950000374996f
#define K2F   0.3989422804014327f   /* 1/sqrt(2*pi) */

__device__ __forceinline__ float med3f(float a, float b, float c){
  return fmaxf(fminf(a,b), fminf(fmaxf(a,b), c));
}
__device__ __forceinline__ float gelu_fast(float v){
  float av = fabsf(v);
  if (__builtin_expect(av > 1.0f, 0))
    return 0.5f * v * (1.0f + erff(v * 0.7071067811865475f));
  float t = v * v;
  float r = 1.3319545e-06f;
  r = fmaf(r, t, -1.8889312e-05f);
  r = fmaf(r, t,  2.3086939e-04f);
  r = fmaf(r, t, -2.3746564e-03f);
  r = fmaf(r, t,  1.9947114e-02f);
  r = fmaf(r, t, -1.3298076e-01f);
  r = fmaf(r, t,  7.9788456e-01f);
  float a = 0.5f * v;
  return fmaf(a * v, r, a);
}
/* e^x for |x| <~ 0.05: cubic Taylor, err < 1e-7 */
__device__ __forceinline__ float exp_t3(float x){
  float t = fmaf(x, 0.3333333333f, 1.0f);
  t = fmaf(x * 0.5f, t, 1.0f);
  return fmaf(x, t, 1.0f);
}
__device__ __forceinline__ float rdlane(float v, int lane){
  return __int_as_float(__builtin_amdgcn_readlane(__float_as_int(v), lane));
}
__device__ __forceinline__ void tstore(u64* p, u32 tag, float v){
  u64 w = ((u64)tag << 32) | (u64)(u32)__float_as_uint(v);
  __hip_atomic_store(p, w, __ATOMIC_RELAXED, __HIP_MEMORY_SCOPE_AGENT);
}
__device__ __forceinline__ float tpoll(const u64* p, u32 tag){
  u64 v;
  do { v = __hip_atomic_load(p, __ATOMIC_RELAXED, __HIP_MEMORY_SCOPE_AGENT); }
  while ((u32)(v >> 32) != tag);
  return __uint_as_float((u32)v);
}

/* sorted-triple merge stage with DPP-shifted operand (identity -1e30 on invalid lanes) */
#define TRIPLE_STAGE(CTRL) { \
  float o1 = __int_as_float(__builtin_amdgcn_update_dpp(ni, __float_as_int(t1), CTRL, 0xf, 0xf, false)); \
  float o2 = __int_as_float(__builtin_amdgcn_update_dpp(ni, __float_as_int(t2), CTRL, 0xf, 0xf, false)); \
  float o3 = __int_as_float(__builtin_amdgcn_update_dpp(ni, __float_as_int(t3), CTRL, 0xf, 0xf, false)); \
  float yy = fminf(t1,o1), xx = fmaxf(t2,o2); \
  t1 = fmaxf(t1,o1); \
  float n3 = med3f(yy, xx, fmaxf(t3,o3)); \
  t2 = fmaxf(yy,xx); t3 = n3; }

/* ------------ K1: coalesced tile-transpose fold (blocks 0..767)
               + QKV/We row-fold, one row per wave (blocks 768..783) ------------ */
__global__ __launch_bounds__(1024) void precompute1_kernel(
    const float* __restrict__ x,   const float* __restrict__ g0,
    const float* __restrict__ b0,
    const float* __restrict__ gg1, const float* __restrict__ bb1,
    const float* __restrict__ gg2, const float* __restrict__ bb2,
    const float* __restrict__ Wagg, const float* __restrict__ bagg,
    const float* __restrict__ We,  const float* __restrict__ be,
    const float* __restrict__ Wq,  const float* __restrict__ bq,
    const float* __restrict__ Wk,
    const float* __restrict__ Wv,  const float* __restrict__ bv,
    float* __restrict__ ws)
{
  const int tid = threadIdx.x;

  if (blockIdx.x < 768) {
    /* fold: xn[b][tim][c] = BN0(x)[b][c][tim]; 4 32x32 tiles per block, coalesced */
    __shared__ float tile[4][32*33];
    const int tau = blockIdx.x*4 + (tid >> 8);         /* 0..3071 */
    const int b   = tau / 192;
    const int rem = tau - b*192;
    const int t0  = (rem % 24) * 32;
    const int c0  = (rem / 24) * 32;
    const int tx  = tid & 31;
    const int ty  = (tid >> 5) & 7;
    float* tl = &tile[tid >> 8][0];
    const long xb = (long)b * (CCH*TT);
    #pragma unroll
    for (int r = 0; r < 4; ++r) {
      int c = c0 + ty + r*8;
      int ict = c*TT + t0 + tx;
      tl[(ty + r*8)*33 + tx] = fmaf(x[xb + ict], g0[ict]*INVSF, b0[ict]);
    }
    __syncthreads();
    #pragma unroll
    for (int r = 0; r < 4; ++r) {
      int tt = t0 + ty + r*8;
      ws[WS_XN + ((long)b*TT + tt)*CCH + c0 + tx] = tl[tx*33 + ty + r*8];
    }
    return;
  }

  /* fold blocks: 16 blocks x 16 waves, one row f per wave */
  __shared__ float We_s[CCH], be_s[CCH];
  const int lane = tid & 63;
  const int w    = tid >> 6;
  if (tid < CCH) { We_s[tid] = We[tid]; be_s[tid] = be[tid]; }
  __syncthreads();

  const int f = (blockIdx.x - 768)*16 + w;
  float aq=0.f, cqa=0.f, ak=0.f, av=0.f, cva=0.f;
  #pragma unroll
  for (int k2 = 0; k2 < 4; ++k2) {
    int j = lane + 64*k2;
    float wev = We_s[j], bev = be_s[j];
    float q1 = Wq[f*CCH + j]; aq += q1*wev; cqa += q1*bev;
    float k1 = Wk[f*CCH + j]; ak += k1*wev;
    float v1 = Wv[f*CCH + j]; av += v1*wev; cva += v1*bev;
  }
  for (int ofs = 1; ofs < 64; ofs <<= 1) {
    aq += __shfl_xor(aq, ofs);  cqa += __shfl_xor(cqa, ofs);
    ak += __shfl_xor(ak, ofs);
    av += __shfl_xor(av, ofs);  cva += __shfl_xor(cva, ofs);
  }
  if (lane == 0) {
    ws[WS_S1Q  + f] = aq;
    ws[WS_S1CQ + f] = cqa + bq[f];
    ws[WS_S1K  + f] = ak;
    ws[WS_S1V  + f] = av;
    ws[WS_S1CV + f] = cva + bv[f];
  }

  if (blockIdx.x == 768) {
    /* small param tables */
    for (int i = tid; i < PT*CCH; i += 1024) {
      int j = i >> 8, c = i & 255;
      ws[WS_G1T + i] = gg1[c*PT + j] * INVSF;
      ws[WS_B1T + i] = bb1[c*PT + j];
      ws[WS_G2T + i] = gg2[c*PT + j] * INVSF;
      ws[WS_B2T + i] = bb2[c*PT + j];
    }
    if (tid < PT*PT) ws[WS_WAGG + tid] = Wagg[tid];
    if (tid < PT)    ws[WS_BAGG + tid] = bagg[tid];
  }
}

/* ------------ K2: Wm1.wv fold (blocks 0..15, row/wave) + Ah/Ch (block 16) ------------ */
__global__ __launch_bounds__(1024) void precompute2_kernel(
    const float* __restrict__ Wm1, const float* __restrict__ bm1,
    float* __restrict__ ws)
{
  const int tid  = threadIdx.x;
  const int lane = tid & 63;
  const int w    = tid >> 6;

  if (blockIdx.x < 16) {
    __shared__ float wv_l[CCH], cv_l[CCH];
    if (tid < CCH) { wv_l[tid] = ws[WS_S1V + tid]; cv_l[tid] = ws[WS_S1CV + tid]; }
    __syncthreads();
    const int g = blockIdx.x*16 + w;
    float mk0=0.f, mk1=0.f, mk2=0.f, mk3=0.f, ca=0.f;
    #pragma unroll
    for (int k2 = 0; k2 < 4; ++k2) {
      int j = lane + 64*k2;
      float wv1 = Wm1[g*CCH + j];
      float pm = wv1 * wv_l[j];
      if (k2 == 0) mk0 = pm; else if (k2 == 1) mk1 = pm; else if (k2 == 2) mk2 = pm; else mk3 = pm;
      ca += wv1 * cv_l[j];
    }
    for (int ofs = 1; ofs < 64; ofs <<= 1) {
      mk0 += __shfl_xor(mk0, ofs); mk1 += __shfl_xor(mk1, ofs);
      mk2 += __shfl_xor(mk2, ofs); mk3 += __shfl_xor(mk3, ofs);
      ca  += __shfl_xor(ca,  ofs);
    }
    if (lane == 0) {
      ws[WS_M + g*4+0] = mk0; ws[WS_M + g*4+1] = mk1;
      ws[WS_M + g*4+2] = mk2; ws[WS_M + g*4+3] = mk3;
      ws[WS_CM1 + g] = ca + bm1[g];
    }
    return;
  }

  /* block 16: per-head Ah/Ch */
  if (tid < NH*64) {
    const int f = w*64 + lane;
    float a  = ws[WS_S1Q + f] * ws[WS_S1K + f];
    float cc = ws[WS_S1CQ + f] * ws[WS_S1K + f];
    for (int ofs = 1; ofs < 64; ofs <<= 1) { a += __shfl_xor(a, ofs); cc += __shfl_xor(cc, ofs); }
    if (lane == 0) { ws[WS_A + w] = a * 0.125f; ws[WS_CCF + w] = cc * 0.125f; }
  }
}

/* poly coefficient m, accumulated over all 256 g with 64 lanes (4 chunks) + wave reduce */
__device__ __forceinline__ float poly_acc(const float* __restrict__ ws,
                                          const float* __restrict__ Wm2,
                                          int m, int l)
{
  float acc = 0.f;
  #pragma unroll
  for (int k = 0; k < 4; ++k) {
    const int g = l + 64*k;
    const float W  = Wm2[g];
    const float cg = ws[WS_CM1 + g];
    float val;
    if (m == 0)      val = fmaf(K2F*cg, cg, 0.5f*cg);
    else if (m <= 4) val = fmaf(2.f*K2F, cg, 0.5f) * ws[WS_M + g*4 + (m-1)];
    else {
      const int u  = m - 5;
      const int hh = (u<4)?0:(u<7)?1:(u<9)?2:3;
      const int kk = (u<4)?u:(u<7)?(u-3):(u<9)?(u-5):3;
      val = K2F * ws[WS_M + g*4 + hh] * ws[WS_M + g*4 + kk] * ((hh==kk)?1.f:2.f);
    }
    acc += W * val;
  }
  for (int ofs = 1; ofs < 64; ofs <<= 1) acc += __shfl_xor(acc, ofs);
  return acc;
}

/* ------------ main: 64 blocks x 768 thr; DPP butterfly; readlane merges ------------ */
__global__ __launch_bounds__(THR) void main_kernel(
    float* __restrict__ ws, float* __restrict__ out,
    const float* __restrict__ Wm2, const float* __restrict__ bm2)
{
  const int blk   = blockIdx.x;
  const int b     = blk & 15;
  const int slice = blk >> 4;          /* 0..3 */
  const int c0    = slice * 64;
  const int tid   = threadIdx.x;
  const int p     = tid >> 6;          /* wave = patch position */
  const int l     = tid & 63;          /* lane = local channel */

  __shared__ float tmp_sh[2][PT][64];          /* 6.1 KB */
  __shared__ float o_buf[3*PT][69];            /* 9.9 KB */
  __shared__ float C_lds[15];

  /* prologue: 15 poly coefficients, one per wave (waves 0-2 take two) */
  {
    float c = poly_acc(ws, Wm2, p, l);
    if (l == 0) C_lds[p] = c + (p == 0 ? bm2[0] : 0.f);
    if (p < 3) {
      float c2 = poly_acc(ws, Wm2, p + 12, l);
      if (l == 0) C_lds[p + 12] = c2;
    }
  }

  const int cg = c0 + l;
  const float g1r = ws[WS_G1T + p*CCH + cg];
  const float b1r = ws[WS_B1T + p*CCH + cg];
  const float g2r = ws[WS_G2T + p*CCH + cg];
  const float b2r = ws[WS_B2T + p*CCH + cg];
  float waggr[PT];
  #pragma unroll
  for (int j = 0; j < PT; ++j) waggr[j] = ws[WS_WAGG + p*PT + j];
  const float baggp = ws[WS_BAGG + p];
  float Ah[NH], Ch[NH];
  #pragma unroll
  for (int h = 0; h < NH; ++h) { Ah[h] = ws[WS_A + h]; Ch[h] = ws[WS_CCF + h]; }
  __syncthreads();

  float C15[15];
  #pragma unroll
  for (int m = 0; m < 15; ++m)
    C15[m] = __int_as_float(__builtin_amdgcn_readfirstlane(__float_as_int(C_lds[m])));

  u64* exBase = ((u64*)(ws + WS_EXF)) + (size_t)(b*PT + p) * (NSL*8);
  u64* exMine = exBase + slice*8;

  const long xb  = (long)b * (CCH*TT);
  const float* xnb = ws + WS_XN + (long)b*(TT*CCH);
  const int ni = __float_as_int(-1e30f);       /* DPP identity */

  /* t = 0 */
  float st = xnb[(long)(0*PT + p)*CCH + cg];
  o_buf[p][l] = st;

  for (int t = 1; t < NPN; ++t) {
    const int par = t & 1;
    const u32 tag = (u32)t;
    const float xv = xnb[((long)t*PT + p)*CCH + cg];   /* prefetch */

    /* phase 1: tmp = BN1(state) */
    tmp_sh[par][p][l] = fmaf(st, g1r, b1r);
    __syncthreads();

    /* phase 2: agg + gelu + residual; s */
    float acc = baggp;
    #pragma unroll
    for (int j = 0; j < PT; ++j)
      acc = fmaf(tmp_sh[par][j][l], waggr[j], acc);
    float res = gelu_fast(acc) + xv;
    float s   = fmaf(res, g2r, b2r);

    /* phase 3: half-wave dual reduction via DPP (lanes 0-31: s, 32-63: -s) */
    const int src = (l & 31) << 1;
    float v0 = __shfl(s, src), v1 = __shfl(s, src + 1);
    float FBloc = 0.f;
    if (slice == 0)
      FBloc = (rdlane(s, 0) + rdlane(s, 1) + rdlane(s, 2)) * (1.0f/3.0f);
    if (l >= 32) { v0 = -v0; v1 = -v1; }
    float t1 = fmaxf(v0, v1), t2 = fminf(v0, v1), t3 = -1e30f;
    TRIPLE_STAGE(0x111);   /* row_shr:1 */
    TRIPLE_STAGE(0x112);   /* row_shr:2 */
    TRIPLE_STAGE(0x114);   /* row_shr:4 */
    TRIPLE_STAGE(0x118);   /* row_shr:8 */
    TRIPLE_STAGE(0x142);   /* row_bcast15 */
    const float lt1 = rdlane(t1, 31), lt2 = rdlane(t2, 31), lt3 = rdlane(t3, 31);
    const float lu1 = rdlane(t1, 63), lu2 = rdlane(t2, 63), lu3 = rdlane(t3, 63);

    /* exchange: post own 6 (+FB on slice0) */
    {
      float sw = (l == 0) ? lt1 : (l == 1) ? lt2 : (l == 2) ? lt3
               : (l == 3) ? lu1 : (l == 4) ? lu2 : lu3;
      if (l < 6) tstore(exMine + l, tag, sw);
      if (slice == 0 && l == 6) tstore(exMine + 6, tag, FBloc);
    }

    /* overlapped flush of step t-2 — moved into the exchange window so the
       store-propagation latency of the posts above is covered by real work */
    if (t >= 2) {
      const int tt   = t - 2;
      const int c    = tid / PT;          /* local channel 0..63 */
      const int part = tid - c*PT;        /* 0..11 */
      out[xb + (long)(c0 + c)*TT + tt*PT + part] = o_buf[(tt % 3)*PT + part][c];
    }

    /* poll 3 peers' 6 (+FB if slice!=0) */
    float pv = 0.f;
    if (l < 18) {
      int pj = l / 6, word = l - pj*6;
      int pslice = pj + (pj >= slice);
      pv = tpoll(exBase + pslice*8 + word, tag);
    } else if (l == 18 && slice != 0) {
      pv = tpoll(exBase + 6, tag);        /* slice0 FB */
    }

    /* merge own triple with 3 peers' via readlane (wave-uniform scalar math) */
    float T1 = lt1, T2 = lt2, T3 = lt3;
    float U1 = lu1, U2 = lu2, U3 = lu3;
    #pragma unroll
    for (int j = 0; j < 3; ++j) {
      const float q1 = rdlane(pv, 6*j),     q2 = rdlane(pv, 6*j + 1), q3 = rdlane(pv, 6*j + 2);
      const float r1 = rdlane(pv, 6*j + 3), r2 = rdlane(pv, 6*j + 4), r3 = rdlane(pv, 6*j + 5);
      float x1 = fminf(T1, q1), y1 = fmaxf(T2, q2);
      T1 = fmaxf(T1, q1);
      float nT3 = med3f(x1, y1, fmaxf(T3, q3));
      T2 = fmaxf(x1, y1); T3 = nT3;
      float x2 = fminf(U1, r1), y2 = fmaxf(U2, r2);
      U1 = fmaxf(U1, r1);
      float nU3 = med3f(x2, y2, fmaxf(U3, r3));
      U2 = fmaxf(x2, y2); U3 = nU3;
    }
    const float FB = (slice == 0) ? FBloc : rdlane(pv, 18);
    const float B1 = -U1, B2 = -U2, B3 = -U3;
    const float Td2 = T2 - T1, Td3 = T3 - T1;
    const float Bd2 = B2 - B1, Bd3 = B3 - B1;

    /* phase 4: S1 per head -> quadratic z -> new state */
    float S1v[NH];
    #pragma unroll
    for (int h = 0; h < NH; ++h) {
      float alpha = fmaf(Ah[h], s, Ch[h]);
      bool pos = alpha > 0.0f;
      float v1s = pos ? T1 : B1;
      float v2s = pos ? T2 : B2;
      float v3s = pos ? T3 : B3;
      float d2 = pos ? Td2 : Bd2;
      float d3 = pos ? Td3 : Bd3;
      float e2 = exp_t3(alpha * d2);
      float e3 = exp_t3(alpha * d3);
      float num = fmaf(e2, v2s, fmaf(e3, v3s, v1s));
      float den = (1.0f + e2) + e3;
      float r = __fdividef(num, den);
      S1v[h] = (alpha == 0.0f) ? FB : r;
    }
    {
      const float a = S1v[0], bq2 = S1v[1], c = S1v[2], d = S1v[3];
      float z = C15[0];
      z = fmaf(C15[1], a, z);  z = fmaf(C15[2], bq2, z);
      z = fmaf(C15[3], c, z);  z = fmaf(C15[4], d, z);
      z = fmaf(C15[5],  a*a, z);   z = fmaf(C15[6],  a*bq2, z);
      z = fmaf(C15[7],  a*c, z);   z = fmaf(C15[8],  a*d, z);
      z = fmaf(C15[9],  bq2*bq2, z); z = fmaf(C15[10], bq2*c, z);
      z = fmaf(C15[11], bq2*d, z); z = fmaf(C15[12], c*c, z);
      z = fmaf(C15[13], c*d, z);   z = fmaf(C15[14], d*d, z);
      st = fmaf(0.5f, z, res);
    }
    o_buf[(t % 3)*PT + p][l] = st;
  }

  /* tail: flush steps 62 and 63 */
  __syncthreads();
  {
    const int c    = tid / PT;
    const int part = tid - c*PT;
    #pragma unroll
    for (int tt = NPN-2; tt < NPN; ++tt)
      out[xb + (long)(c0 + c)*TT + tt*PT + part] = o_buf[(tt % 3)*PT + part][c];
  }
}

extern "C" void kernel_launch(void* const* d_in, const int* in_sizes, int n_in,
                              void* d_out, int out_size, void* d_ws, size_t ws_size,
                              hipStream_t stream) {
  (void)in_sizes; (void)n_in; (void)out_size; (void)ws_size;
  const float* x    = (const float*)d_in[0];
  const float* g0   = (const float*)d_in[1];
  const float* b0   = (const float*)d_in[2];
  const float* gg1  = (const float*)d_in[3];
  const float* bb1  = (const float*)d_in[4];
  const float* gg2  = (const float*)d_in[5];
  const float* bb2  = (const float*)d_in[6];
  const float* Wagg = (const float*)d_in[7];
  const float* bagg = (const float*)d_in[8];
  const float* We   = (const float*)d_in[9];
  const float* be   = (const float*)d_in[10];
  const float* Wq   = (const float*)d_in[11];
  const float* bq   = (const float*)d_in[12];
  const float* Wk   = (const float*)d_in[13];
  /* bk (d_in[14]) provably drops out: softmax over e of alpha*s_e + beta(c) is beta-invariant */
  const float* Wv   = (const float*)d_in[15];
  const float* bv   = (const float*)d_in[16];
  const float* Wm1  = (const float*)d_in[17];
  const float* bm1  = (const float*)d_in[18];
  const float* Wm2  = (const float*)d_in[19];
  const float* bm2  = (const float*)d_in[20];
  float* ws  = (float*)d_ws;
  float* out = (float*)d_out;

  hipLaunchKernelGGL(precompute1_kernel, dim3(768 + 16), dim3(1024), 0, stream,
                     x, g0, b0, gg1, bb1, gg2, bb2, Wagg, bagg, We, be,
                     Wq, bq, Wk, Wv, bv, ws);
  hipLaunchKernelGGL(precompute2_kernel, dim3(17), dim3(1024), 0, stream,
                     Wm1, bm1, ws);
  hipLaunchKernelGGL(main_kernel, dim3(GRID), dim3(THR), 0, stream, ws, out, Wm2, bm2);
}